// Round 3
// baseline (952.465 us; speedup 1.0000x reference)
//
#include <hip/hip_runtime.h>
#include <hip/hip_bf16.h>
#include <math.h>

typedef float f32x4 __attribute__((ext_vector_type(4)));
typedef __bf16 bf16x8 __attribute__((ext_vector_type(8)));
typedef __bf16 bf16x4 __attribute__((ext_vector_type(4)));
typedef unsigned int u32x4 __attribute__((ext_vector_type(4)));
typedef unsigned long long u64;

#define BATCH   64
#define TSTEPS  39
#define HID     512
#define GATES   2048
#define NVOCAB  32000
#define EMBD    300
#define FEAT    1024
#define XDIM    1324

#define PRED_ELEMS (BATCH*TSTEPS*NVOCAB)   // 79,872,000

// ws offsets (bytes), all 16B aligned
#define WS_CNT     0
#define WS_SORT    256
#define WS_DECLEN  512
#define WS_CAPS    1024
#define WS_LT      65536
#define WS_CONST   327680
#define WS_XP      1048576      // [39][2048][64] f32
#define WS_HALL    22020096     // [39][64][512] bf16
#define WS_WDCB    25165824     // [32000][512] bf16

// Agent-scope (device-coherent, L2-bypassing) helpers, relaxed ordering.
// No buffer_inv / buffer_wbl2 is emitted for these — cross-block h exchange
// is synchronized purely by data sentinels (h_all pre-filled with 0xFFFFFFFF,
// a bf16 NaN-pair that sigmoid*tanh can never produce).
__device__ __forceinline__ u64 agent_load_u64(const u64* p) {
    return __hip_atomic_load(p, __ATOMIC_RELAXED, __HIP_MEMORY_SCOPE_AGENT);
}
__device__ __forceinline__ void agent_store_u32(unsigned int* p, unsigned int v) {
    __hip_atomic_store(p, v, __ATOMIC_RELAXED, __HIP_MEMORY_SCOPE_AGENT);
}

// ---------------- K0: sort + caps gather + tail outputs ----------------
__global__ void k0_setup(const int* caplen, const int* enc,
                         float* out_caps, float* out_declen, float* out_sort,
                         int* ws_sort, int* ws_declen, int* ws_caps) {
    __shared__ int L[BATCH];
    __shared__ int sind[BATCH];
    int tid = threadIdx.x;
    if (tid < BATCH) L[tid] = caplen[tid];
    __syncthreads();
    if (tid < BATCH) {
        int len = L[tid];
        int rank = 0;
        for (int j = 0; j < BATCH; ++j) {
            int lj = L[j];
            if (lj > len || (lj == len && j < tid)) rank++;
        }
        sind[rank] = tid;   // stable descending argsort(-lengths)
    }
    __syncthreads();
    if (tid < BATCH) {
        int src = sind[tid];
        ws_sort[tid] = src;
        int dl = L[src] - 1;
        ws_declen[tid] = dl;
        out_declen[tid] = (float)dl;
        out_sort[tid] = (float)src;
    }
    __syncthreads();
    for (int x = tid; x < BATCH*40; x += blockDim.x) {
        int b = x / 40, t = x % 40;
        int v = enc[sind[b]*40 + t];
        ws_caps[x] = v;
        out_caps[x] = (float)v;
    }
}

// ---------------- K1: lt[b][k] = sum_s l_total[s][sort[b]][k] ----------------
__global__ void k1_lt(const float* l_total, const int* ws_sort, float* lt) {
    int b = blockIdx.x;
    int ob = ws_sort[b];
    for (int k4 = threadIdx.x; k4 < FEAT/4; k4 += blockDim.x) {
        float4 a = ((const float4*)(l_total + (0*BATCH + ob)*FEAT))[k4];
        float4 c = ((const float4*)(l_total + (1*BATCH + ob)*FEAT))[k4];
        float4 d = ((const float4*)(l_total + (2*BATCH + ob)*FEAT))[k4];
        float4 r;
        r.x = a.x + c.x + d.x;  r.y = a.y + c.y + d.y;
        r.z = a.z + c.z + d.z;  r.w = a.w + c.w + d.w;
        ((float4*)(lt + b*FEAT))[k4] = r;
    }
}

// ---------------- K2: const[c][b] = bias[c] + sum_k lt[b][k]*W_ih[c][300+k] ----------------
__global__ void k2_const(const float* W_ih, const float* lt,
                         const float* b_ih, const float* b_hh, float* cst) {
    __shared__ float As[32][68];
    __shared__ float Bs[32][36];
    int ctile = blockIdx.x;   // 0..31
    int btile = blockIdx.y;   // 0..1
    int tid = threadIdx.x;
    int ty = tid >> 4, tx = tid & 15;
    float acc[4][2] = {};
    for (int kc = 0; kc < 32; ++kc) {
        __syncthreads();
        #pragma unroll
        for (int j = 0; j < 8; ++j) {
            int idx = tid + j*256;
            int c = idx >> 5, k = idx & 31;
            As[k][c] = W_ih[(ctile*64 + c)*XDIM + 300 + kc*32 + k];
        }
        #pragma unroll
        for (int j = 0; j < 4; ++j) {
            int idx = tid + j*256;
            int b = idx >> 5, k = idx & 31;
            Bs[k][b] = lt[(btile*32 + b)*FEAT + kc*32 + k];
        }
        __syncthreads();
        for (int k = 0; k < 32; ++k) {
            float4 av = *(const float4*)&As[k][ty*4];
            float2 bv = *(const float2*)&Bs[k][tx*2];
            acc[0][0] += av.x*bv.x; acc[0][1] += av.x*bv.y;
            acc[1][0] += av.y*bv.x; acc[1][1] += av.y*bv.y;
            acc[2][0] += av.z*bv.x; acc[2][1] += av.z*bv.y;
            acc[3][0] += av.w*bv.x; acc[3][1] += av.w*bv.y;
        }
    }
    #pragma unroll
    for (int i = 0; i < 4; ++i) {
        int cg = ctile*64 + ty*4 + i;
        float bias = b_ih[cg] + b_hh[cg];
        float2 o;
        o.x = acc[i][0] + bias; o.y = acc[i][1] + bias;
        *(float2*)&cst[cg*64 + btile*32 + tx*2] = o;
    }
}

// ---------------- K3: Xp[t][c][b] = const[c][b] + sum_{k<300} emb[tok[t,b]][k]*W_ih[c][k] ----------------
__global__ void k3_xp(const float* W_ih, const float* emb, const int* ws_caps,
                      const float* cst, float* Xp) {
    __shared__ float As[20][68];
    __shared__ float Bs[20][68];
    int ctile = blockIdx.x;   // 0..31
    int t = blockIdx.y;       // 0..38
    int tid = threadIdx.x;
    int ty = tid >> 4, tx = tid & 15;
    float acc[4][4] = {};
    for (int kc = 0; kc < 15; ++kc) {
        __syncthreads();
        #pragma unroll
        for (int j = 0; j < 5; ++j) {
            int idx = tid + j*256;   // 1280
            int c = idx / 20, k = idx % 20;
            As[k][c] = W_ih[(ctile*64 + c)*XDIM + kc*20 + k];
        }
        #pragma unroll
        for (int j = 0; j < 5; ++j) {
            int idx = tid + j*256;
            int b = idx / 20, k = idx % 20;
            int tok = ws_caps[b*40 + t];
            Bs[k][b] = emb[tok*EMBD + kc*20 + k];
        }
        __syncthreads();
        for (int k = 0; k < 20; ++k) {
            float4 av = *(const float4*)&As[k][ty*4];
            float4 bv = *(const float4*)&Bs[k][tx*4];
            acc[0][0] += av.x*bv.x; acc[0][1] += av.x*bv.y; acc[0][2] += av.x*bv.z; acc[0][3] += av.x*bv.w;
            acc[1][0] += av.y*bv.x; acc[1][1] += av.y*bv.y; acc[1][2] += av.y*bv.z; acc[1][3] += av.y*bv.w;
            acc[2][0] += av.z*bv.x; acc[2][1] += av.z*bv.y; acc[2][2] += av.z*bv.z; acc[2][3] += av.z*bv.w;
            acc[3][0] += av.w*bv.x; acc[3][1] += av.w*bv.y; acc[3][2] += av.w*bv.z; acc[3][3] += av.w*bv.w;
        }
    }
    #pragma unroll
    for (int i = 0; i < 4; ++i) {
        int cg = ctile*64 + ty*4 + i;
        float4 cs = *(const float4*)&cst[cg*64 + tx*4];
        float4 o;
        o.x = acc[i][0] + cs.x; o.y = acc[i][1] + cs.y;
        o.z = acc[i][2] + cs.z; o.w = acc[i][3] + cs.w;
        *(float4*)&Xp[(t*GATES + cg)*64 + tx*4] = o;
    }
}

// ---------------- K4: wdc_W fp32 -> bf16, + sentinel-fill h_all ----------------
__global__ void k4_cvt(const float* wdc, __bf16* wdcb, u32x4* hsent) {
    int gid = blockIdx.x*blockDim.x + threadIdx.x;
    int stride = gridDim.x*blockDim.x;
    int n4 = NVOCAB*HID/4;
    for (int i = gid; i < n4; i += stride) {
        float4 v = ((const float4*)wdc)[i];
        bf16x4 o;
        o[0] = (__bf16)v.x; o[1] = (__bf16)v.y; o[2] = (__bf16)v.z; o[3] = (__bf16)v.w;
        ((bf16x4*)wdcb)[i] = o;
    }
    // h_all sentinel: 0xFFFFFFFF dwords (bf16 NaN pair — unreachable as real h)
    int nh16 = TSTEPS*BATCH*HID*2/16;   // 159,744 16B chunks
    u32x4 s = {0xFFFFFFFFu, 0xFFFFFFFFu, 0xFFFFFFFFu, 0xFFFFFFFFu};
    for (int i = gid; i < nh16; i += stride) hsent[i] = s;
}

// ---------------- K5: persistent LSTM recurrence, DATAFLOW-synchronized ----------------
// Block p owns hidden units [8p, 8p+8): 32 gate rows {q*512 + 8p + ul}.
// W_hh fragments (bf16) live in registers.
// NO grid barrier, NO flags: h_all is pre-filled with the 0xFFFFFFFF sentinel;
// consumers load fragments and re-poll any dword still equal to the sentinel.
// Each dword of h is written exactly once (single-copy-atomic agent store), so
// "dword != sentinel" <=> final data. Producers never wait on consumers and h
// slots are never reused -> deadlock-free; blocks free-run with slack 1 step.
__global__ void __launch_bounds__(256) k5_lstm(const float* W_hh, const float* Xp,
                                               __bf16* h_all) {
    __shared__ float gates_lds[32][64];
    __shared__ float c_lds[8][64];
    __shared__ __bf16 h_s[64][8];       // staging for coalesced h store
    int p = blockIdx.x;
    int tid = threadIdx.x;
    int l = tid & 63, w = tid >> 6;

    // Preload W fragments: A[m=l&15][k=(l>>4)*8+j] for 2 row-tiles x 16 K-chunks
    bf16x8 wfrag[2][16];
    #pragma unroll
    for (int mt = 0; mt < 2; ++mt) {
        int rr = mt*16 + (l & 15);
        int grow = (rr >> 3)*HID + p*8 + (rr & 7);
        const float* wrow = W_hh + grow*HID;
        #pragma unroll
        for (int kc = 0; kc < 16; ++kc) {
            int k0 = kc*32 + (l >> 4)*8;
            float4 f0 = *(const float4*)(wrow + k0);
            float4 f1 = *(const float4*)(wrow + k0 + 4);
            bf16x8 v;
            v[0]=(__bf16)f0.x; v[1]=(__bf16)f0.y; v[2]=(__bf16)f0.z; v[3]=(__bf16)f0.w;
            v[4]=(__bf16)f1.x; v[5]=(__bf16)f1.y; v[6]=(__bf16)f1.z; v[7]=(__bf16)f1.w;
            wfrag[mt][kc] = v;
        }
    }
    for (int x = tid; x < 8*64; x += 256) ((float*)c_lds)[x] = 0.0f;
    __syncthreads();

    int ulA = tid >> 6;     // 0..3 (thread also handles ulA+4)
    int bA  = tid & 63;

    for (int t = 0; t < TSTEPS; ++t) {
        // Prefetch this step's Xp gate-biases into registers. Xp is precomputed
        // (no cross-block dependency) so these loads hide under the poll/MFMA phase.
        float xg[2][4];
        {
            const float* xpt = Xp + (size_t)t*GATES*64;
            int u0 = p*8 + ulA;
            #pragma unroll
            for (int g = 0; g < 4; ++g) {
                xg[0][g] = xpt[((size_t)g*512 + u0    )*64 + bA];
                xg[1][g] = xpt[((size_t)g*512 + u0 + 4)*64 + bA];
            }
        }

        if (t == 0) {
            for (int x = tid; x < 32*64; x += 256) ((float*)gates_lds)[x] = 0.0f;
        } else {
            int bb = w*16 + (l & 15);
            // fragment base: k-offset (l>>4)*8 bf16; chunk stride 32 bf16 = 64 B = 8 u64
            // (round-0 had kc*4 here = 32 B stride — K-coverage bug, fixed)
            const u64* hq = (const u64*)(h_all + (size_t)(t-1)*BATCH*HID + bb*HID + (l >> 4)*8);
            u64 hl[16][2];
            #pragma unroll
            for (int kc = 0; kc < 16; ++kc) {
                hl[kc][0] = agent_load_u64(hq + kc*8);
                hl[kc][1] = agent_load_u64(hq + kc*8 + 1);
            }
            // sentinel re-poll sweep: re-load any fragment half with a NaN-pair dword
            bool dirty = true;
            while (dirty) {
                dirty = false;
                #pragma unroll
                for (int kc = 0; kc < 16; ++kc) {
                    #pragma unroll
                    for (int j = 0; j < 2; ++j) {
                        u64 v = hl[kc][j];
                        if ((unsigned int)v == 0xFFFFFFFFu ||
                            (unsigned int)(v >> 32) == 0xFFFFFFFFu) {
                            hl[kc][j] = agent_load_u64(hq + kc*8 + j);
                            dirty = true;
                        }
                    }
                }
            }
            f32x4 acc0 = {0.f,0.f,0.f,0.f};
            f32x4 acc1 = {0.f,0.f,0.f,0.f};
            #pragma unroll
            for (int kc = 0; kc < 16; ++kc) {
                union { bf16x8 v; u64 u[2]; } uu;
                uu.u[0] = hl[kc][0]; uu.u[1] = hl[kc][1];
                acc0 = __builtin_amdgcn_mfma_f32_16x16x32_bf16(wfrag[0][kc], uu.v, acc0, 0, 0, 0);
                acc1 = __builtin_amdgcn_mfma_f32_16x16x32_bf16(wfrag[1][kc], uu.v, acc1, 0, 0, 0);
            }
            #pragma unroll
            for (int j = 0; j < 4; ++j) {
                gates_lds[(l>>4)*4 + j][bb]      = acc0[j];
                gates_lds[16 + (l>>4)*4 + j][bb] = acc1[j];
            }
        }
        __syncthreads();

        // cell update: 8 units x 64 batches -> 2 items/thread; h into LDS staging
        #pragma unroll
        for (int half = 0; half < 2; ++half) {
            int ul = ulA + half*4;
            int b  = bA;
            float gi = gates_lds[ul][b]      + xg[half][0];
            float gf = gates_lds[8+ul][b]    + xg[half][1];
            float gg = gates_lds[16+ul][b]   + xg[half][2];
            float go = gates_lds[24+ul][b]   + xg[half][3];
            float ig = 1.0f/(1.0f + expf(-gi));
            float fg = 1.0f/(1.0f + expf(-gf));
            float gv = tanhf(gg);
            float og = 1.0f/(1.0f + expf(-go));
            float c = fg * c_lds[ul][b] + ig * gv;
            c_lds[ul][b] = c;
            float h = og * tanhf(c);
            h_s[b][ul] = (__bf16)h;
        }
        __syncthreads();   // h_s complete (also orders gates_lds reuse next step)

        // coalesced agent store: 64 rows x 16B, one dword per thread; no drain —
        // consumers' sentinel polls provide the synchronization.
        {
            int row = tid >> 2, seg = tid & 3;
            unsigned int val = ((const unsigned int*)&h_s[0][0])[row*4 + seg];
            unsigned int* dst = (unsigned int*)(h_all + ((size_t)t*BATCH + row)*HID + p*8);
            agent_store_u32(dst + seg, val);
        }
    }
}

// ---------------- K6: pred = h_all @ wdc_W^T + b, masked, 128x128 bf16 MFMA tiles ----------------
// Grid: x = mtile (fast, 20) so the blocks sharing one wdcb B-tile land
// round-robin across the 8 XCDs -> each B-tile fetched <=8x from LLC.
__global__ void __launch_bounds__(256) k6_pred(const __bf16* h_all, const __bf16* wdcb,
                                               const float* wdc_b, const int* ws_declen,
                                               float* out) {
    __shared__ __bf16 As[128][40];
    __shared__ __bf16 Bs[128][40];
    int mtile = blockIdx.x;   // 0..19  (M padded 2496->2560)
    int ntile = blockIdx.y;   // 0..249
    int tid = threadIdx.x;
    int l = tid & 63, w = tid >> 6;
    int wm = w >> 1, wn = w & 1;

    f32x4 acc[4][4];
    #pragma unroll
    for (int i = 0; i < 4; ++i)
        #pragma unroll
        for (int j = 0; j < 4; ++j)
            acc[i][j] = (f32x4){0.f,0.f,0.f,0.f};

    for (int kc = 0; kc < 16; ++kc) {
        __syncthreads();
        #pragma unroll
        for (int j = 0; j < 2; ++j) {
            int idx = tid + j*256;      // 0..511
            int row = idx >> 2, seg = idx & 3;
            int rg = mtile*128 + row;
            bf16x8 v;
            if (rg < TSTEPS*BATCH) {
                v = *(const bf16x8*)(h_all + (size_t)rg*HID + kc*32 + seg*8);
            } else {
                #pragma unroll
                for (int q = 0; q < 8; ++q) v[q] = (__bf16)0.0f;
            }
            *(bf16x8*)&As[row][seg*8] = v;
            int cg = ntile*128 + row;
            *(bf16x8*)&Bs[row][seg*8] = *(const bf16x8*)(wdcb + (size_t)cg*HID + kc*32 + seg*8);
        }
        __syncthreads();
        bf16x8 af[4], bf[4];
        #pragma unroll
        for (int s = 0; s < 4; ++s) {
            af[s] = *(const bf16x8*)&As[wm*64 + s*16 + (l & 15)][(l >> 4)*8];
            bf[s] = *(const bf16x8*)&Bs[wn*64 + s*16 + (l & 15)][(l >> 4)*8];
        }
        #pragma unroll
        for (int sm = 0; sm < 4; ++sm)
            #pragma unroll
            for (int sn = 0; sn < 4; ++sn)
                acc[sm][sn] = __builtin_amdgcn_mfma_f32_16x16x32_bf16(af[sm], bf[sn], acc[sm][sn], 0, 0, 0);
    }

    #pragma unroll
    for (int sm = 0; sm < 4; ++sm) {
        #pragma unroll
        for (int j = 0; j < 4; ++j) {
            int R = mtile*128 + wm*64 + sm*16 + (l >> 4)*4 + j;
            if (R >= TSTEPS*BATCH) continue;
            int t = R >> 6, b = R & 63;
            int dl = ws_declen[b];
            #pragma unroll
            for (int sn = 0; sn < 4; ++sn) {
                int C = ntile*128 + wn*64 + sn*16 + (l & 15);
                float v = (t < dl) ? (acc[sm][sn][j] + wdc_b[C]) : 0.0f;
                out[((size_t)b*TSTEPS + t)*NVOCAB + C] = v;
            }
        }
    }
}

extern "C" void kernel_launch(void* const* d_in, const int* in_sizes, int n_in,
                              void* d_out, int out_size, void* d_ws, size_t ws_size,
                              hipStream_t stream) {
    const float* l_total = (const float*)d_in[0];
    const int*   enc     = (const int*)d_in[1];
    const int*   caplen  = (const int*)d_in[2];
    const float* emb     = (const float*)d_in[3];
    const float* W_ih    = (const float*)d_in[4];
    const float* W_hh    = (const float*)d_in[5];
    const float* b_ih    = (const float*)d_in[6];
    const float* b_hh    = (const float*)d_in[7];
    const float* wdc_W   = (const float*)d_in[8];
    const float* wdc_b   = (const float*)d_in[9];

    float* out = (float*)d_out;
    char* ws = (char*)d_ws;

    int* ws_sort        = (int*)(ws + WS_SORT);
    int* ws_declen      = (int*)(ws + WS_DECLEN);
    int* ws_caps        = (int*)(ws + WS_CAPS);
    float* lt           = (float*)(ws + WS_LT);
    float* cst          = (float*)(ws + WS_CONST);
    float* Xp           = (float*)(ws + WS_XP);
    __bf16* h_all       = (__bf16*)(ws + WS_HALL);
    __bf16* wdcb        = (__bf16*)(ws + WS_WDCB);

    float* out_caps   = out + PRED_ELEMS;
    float* out_declen = out_caps + BATCH*40;
    float* out_sort   = out_declen + BATCH;

    k0_setup<<<1, 256, 0, stream>>>(caplen, enc, out_caps, out_declen, out_sort,
                                    ws_sort, ws_declen, ws_caps);
    k1_lt<<<BATCH, 256, 0, stream>>>(l_total, ws_sort, lt);
    k2_const<<<dim3(32, 2), 256, 0, stream>>>(W_ih, lt, b_ih, b_hh, cst);
    k3_xp<<<dim3(32, TSTEPS), 256, 0, stream>>>(W_ih, emb, ws_caps, cst, Xp);
    k4_cvt<<<2048, 256, 0, stream>>>(wdc_W, wdcb, (u32x4*)h_all);
    k5_lstm<<<64, 256, 0, stream>>>(W_hh, Xp, h_all);
    k6_pred<<<dim3(20, NVOCAB/128), 256, 0, stream>>>(h_all, wdcb, wdc_b, ws_declen, out);
}

// Round 4
// 939.983 us; speedup vs baseline: 1.0133x; 1.0133x over previous
//
#include <hip/hip_runtime.h>
#include <hip/hip_bf16.h>
#include <math.h>

typedef float f32x4 __attribute__((ext_vector_type(4)));
typedef __bf16 bf16x8 __attribute__((ext_vector_type(8)));
typedef __bf16 bf16x4 __attribute__((ext_vector_type(4)));
typedef unsigned long long u64;

#define BATCH   64
#define TSTEPS  39
#define HID     512
#define GATES   2048
#define NVOCAB  32000
#define EMBD    300
#define FEAT    1024
#define XDIM    1324

#define PRED_ELEMS (BATCH*TSTEPS*NVOCAB)   // 79,872,000

#define NT_M 20          // mtiles (rows 2560, M=2496 padded)
#define NT_N 250         // ntiles (32000/128)
#define TOT_TILES (NT_M*NT_N)
#define REC_BLOCKS 64
#define GRID_BLOCKS 256

// ws offsets (bytes), all 16B aligned
#define WS_STEPDONE 0
#define WS_TILECNT  128
#define WS_SORT     256
#define WS_DECLEN   512
#define WS_CAPS     1024
#define WS_BAR      16384       // 64 arrival flags, 128B apart (8 KB)
#define WS_LT       65536
#define WS_CONST    327680
#define WS_XP       1048576     // [39][2048][64] f32
#define WS_HALL     22020096    // [39][64][512] bf16
#define WS_WDCB     25165824    // [32000][512] bf16

// Agent-scope (device-coherent, L1/L2-bypassing) relaxed helpers. No
// buffer_inv / buffer_wbl2 is emitted; ordering is built by hand from
// __syncthreads() vmcnt-drains + the flag/step_done protocol.
__device__ __forceinline__ u64 agent_load_u64(const u64* p) {
    return __hip_atomic_load(p, __ATOMIC_RELAXED, __HIP_MEMORY_SCOPE_AGENT);
}
__device__ __forceinline__ unsigned int agent_load_u32(const unsigned int* p) {
    return __hip_atomic_load(p, __ATOMIC_RELAXED, __HIP_MEMORY_SCOPE_AGENT);
}
__device__ __forceinline__ void agent_store_u32(unsigned int* p, unsigned int v) {
    __hip_atomic_store(p, v, __ATOMIC_RELAXED, __HIP_MEMORY_SCOPE_AGENT);
}

// ---------------- K0: sort + caps gather + tail outputs + sync-state zero ----------------
__global__ void k0_setup(const int* caplen, const int* enc,
                         float* out_caps, float* out_declen, float* out_sort,
                         int* ws_sort, int* ws_declen, int* ws_caps,
                         unsigned int* step_done, unsigned int* tile_cnt,
                         unsigned int* bar) {
    __shared__ int L[BATCH];
    __shared__ int sind[BATCH];
    int tid = threadIdx.x;
    if (tid == 0) { *step_done = 0u; *tile_cnt = 0u; }
    for (int x = tid; x < 64*32; x += blockDim.x) bar[x] = 0u;
    if (tid < BATCH) L[tid] = caplen[tid];
    __syncthreads();
    if (tid < BATCH) {
        int len = L[tid];
        int rank = 0;
        for (int j = 0; j < BATCH; ++j) {
            int lj = L[j];
            if (lj > len || (lj == len && j < tid)) rank++;
        }
        sind[rank] = tid;   // stable descending argsort(-lengths)
    }
    __syncthreads();
    if (tid < BATCH) {
        int src = sind[tid];
        ws_sort[tid] = src;
        int dl = L[src] - 1;
        ws_declen[tid] = dl;
        out_declen[tid] = (float)dl;
        out_sort[tid] = (float)src;
    }
    __syncthreads();
    for (int x = tid; x < BATCH*40; x += blockDim.x) {
        int b = x / 40, t = x % 40;
        int v = enc[sind[b]*40 + t];
        ws_caps[x] = v;
        out_caps[x] = (float)v;
    }
}

// ---------------- K1: lt[b][k] = sum_s l_total[s][sort[b]][k] ----------------
__global__ void k1_lt(const float* l_total, const int* ws_sort, float* lt) {
    int b = blockIdx.x;
    int ob = ws_sort[b];
    for (int k4 = threadIdx.x; k4 < FEAT/4; k4 += blockDim.x) {
        float4 a = ((const float4*)(l_total + (0*BATCH + ob)*FEAT))[k4];
        float4 c = ((const float4*)(l_total + (1*BATCH + ob)*FEAT))[k4];
        float4 d = ((const float4*)(l_total + (2*BATCH + ob)*FEAT))[k4];
        float4 r;
        r.x = a.x + c.x + d.x;  r.y = a.y + c.y + d.y;
        r.z = a.z + c.z + d.z;  r.w = a.w + c.w + d.w;
        ((float4*)(lt + b*FEAT))[k4] = r;
    }
}

// ---------------- K2: const[c][b] = bias[c] + sum_k lt[b][k]*W_ih[c][300+k] ----------------
__global__ void k2_const(const float* W_ih, const float* lt,
                         const float* b_ih, const float* b_hh, float* cst) {
    __shared__ float As[32][68];
    __shared__ float Bs[32][36];
    int ctile = blockIdx.x;   // 0..31
    int btile = blockIdx.y;   // 0..1
    int tid = threadIdx.x;
    int ty = tid >> 4, tx = tid & 15;
    float acc[4][2] = {};
    for (int kc = 0; kc < 32; ++kc) {
        __syncthreads();
        #pragma unroll
        for (int j = 0; j < 8; ++j) {
            int idx = tid + j*256;
            int c = idx >> 5, k = idx & 31;
            As[k][c] = W_ih[(ctile*64 + c)*XDIM + 300 + kc*32 + k];
        }
        #pragma unroll
        for (int j = 0; j < 4; ++j) {
            int idx = tid + j*256;
            int b = idx >> 5, k = idx & 31;
            Bs[k][b] = lt[(btile*32 + b)*FEAT + kc*32 + k];
        }
        __syncthreads();
        for (int k = 0; k < 32; ++k) {
            float4 av = *(const float4*)&As[k][ty*4];
            float2 bv = *(const float2*)&Bs[k][tx*2];
            acc[0][0] += av.x*bv.x; acc[0][1] += av.x*bv.y;
            acc[1][0] += av.y*bv.x; acc[1][1] += av.y*bv.y;
            acc[2][0] += av.z*bv.x; acc[2][1] += av.z*bv.y;
            acc[3][0] += av.w*bv.x; acc[3][1] += av.w*bv.y;
        }
    }
    #pragma unroll
    for (int i = 0; i < 4; ++i) {
        int cg = ctile*64 + ty*4 + i;
        float bias = b_ih[cg] + b_hh[cg];
        float2 o;
        o.x = acc[i][0] + bias; o.y = acc[i][1] + bias;
        *(float2*)&cst[cg*64 + btile*32 + tx*2] = o;
    }
}

// ---------------- K3: Xp[t][c][b] = const[c][b] + sum_{k<300} emb[tok[t,b]][k]*W_ih[c][k] ----------------
__global__ void k3_xp(const float* W_ih, const float* emb, const int* ws_caps,
                      const float* cst, float* Xp) {
    __shared__ float As[20][68];
    __shared__ float Bs[20][68];
    int ctile = blockIdx.x;   // 0..31
    int t = blockIdx.y;       // 0..38
    int tid = threadIdx.x;
    int ty = tid >> 4, tx = tid & 15;
    float acc[4][4] = {};
    for (int kc = 0; kc < 15; ++kc) {
        __syncthreads();
        #pragma unroll
        for (int j = 0; j < 5; ++j) {
            int idx = tid + j*256;   // 1280
            int c = idx / 20, k = idx % 20;
            As[k][c] = W_ih[(ctile*64 + c)*XDIM + kc*20 + k];
        }
        #pragma unroll
        for (int j = 0; j < 5; ++j) {
            int idx = tid + j*256;
            int b = idx / 20, k = idx % 20;
            int tok = ws_caps[b*40 + t];
            Bs[k][b] = emb[tok*EMBD + kc*20 + k];
        }
        __syncthreads();
        for (int k = 0; k < 20; ++k) {
            float4 av = *(const float4*)&As[k][ty*4];
            float4 bv = *(const float4*)&Bs[k][tx*4];
            acc[0][0] += av.x*bv.x; acc[0][1] += av.x*bv.y; acc[0][2] += av.x*bv.z; acc[0][3] += av.x*bv.w;
            acc[1][0] += av.y*bv.x; acc[1][1] += av.y*bv.y; acc[1][2] += av.y*bv.z; acc[1][3] += av.y*bv.w;
            acc[2][0] += av.z*bv.x; acc[2][1] += av.z*bv.y; acc[2][2] += av.z*bv.z; acc[2][3] += av.z*bv.w;
            acc[3][0] += av.w*bv.x; acc[3][1] += av.w*bv.y; acc[3][2] += av.w*bv.z; acc[3][3] += av.w*bv.w;
        }
    }
    #pragma unroll
    for (int i = 0; i < 4; ++i) {
        int cg = ctile*64 + ty*4 + i;
        float4 cs = *(const float4*)&cst[cg*64 + tx*4];
        float4 o;
        o.x = acc[i][0] + cs.x; o.y = acc[i][1] + cs.y;
        o.z = acc[i][2] + cs.z; o.w = acc[i][3] + cs.w;
        *(float4*)&Xp[(t*GATES + cg)*64 + tx*4] = o;
    }
}

// ---------------- K4: wdc_W fp32 -> bf16 ----------------
__global__ void k4_cvt(const float* wdc, __bf16* wdcb) {
    int n4 = NVOCAB*HID/4;
    for (int i = blockIdx.x*blockDim.x + threadIdx.x; i < n4; i += gridDim.x*blockDim.x) {
        float4 v = ((const float4*)wdc)[i];
        bf16x4 o;
        o[0] = (__bf16)v.x; o[1] = (__bf16)v.y; o[2] = (__bf16)v.z; o[3] = (__bf16)v.w;
        ((bf16x4*)wdcb)[i] = o;
    }
}

// ---------------- K5 (fused): LSTM recurrence + streaming pred GEMM ----------------
// Blocks 0..63: recurrence (block p owns hidden units [8p,8p+8), flag barrier
//   per step, p==0 publishes step_done = t+1 after observing all 64 flags).
// Blocks 64..255 (+ rec blocks once done): persistent pred workers. Grab tile
//   off tile_cnt (mtile-major), wait step_done to cover the tile's t-range,
//   then run the 128x128 bf16 MFMA tile (old k6 body).
// Residency: 256 blocks x 256 thr x 20.5KB LDS -> all co-resident on 256 CUs
//   even at 2 blocks/CU worst case; pred never blocks rec -> deadlock-free.
// Freshness: h_all is touched ONLY via sc1 (agent) ops by rec; pred's plain
//   loads first-touch each line after step_done covers it -> L1/L2 miss ->
//   fresh from LLC. step_done/bar/tile_cnt always sc1.
__global__ void __launch_bounds__(256) k5_fused(const float* W_hh, const float* Xp,
                                                __bf16* h_all, unsigned int* bar,
                                                unsigned int* step_done, unsigned int* tile_cnt,
                                                const __bf16* wdcb, const float* wdc_b,
                                                const int* ws_declen, float* out) {
    __shared__ __align__(16) char lds_raw[20480];
    __shared__ unsigned int tile_sh;
    int tid = threadIdx.x;
    int l = tid & 63, w = tid >> 6;

    if (blockIdx.x < REC_BLOCKS) {
        // ================= recurrence =================
        float (*gates_lds)[64] = (float(*)[64])(lds_raw);              // 32x64 f32 = 8KB
        float (*c_lds)[64]     = (float(*)[64])(lds_raw + 8192);       // 8x64 f32  = 2KB
        __bf16 (*h_s)[8]       = (__bf16(*)[8])(lds_raw + 10240);      // 64x8 bf16 = 1KB
        int p = blockIdx.x;

        __builtin_amdgcn_s_setprio(1);   // rec is the critical path; win issue
                                         // arbitration vs co-resident pred waves

        // Preload W fragments: 2 row-tiles x 16 K-chunks
        bf16x8 wfrag[2][16];
        #pragma unroll
        for (int mt = 0; mt < 2; ++mt) {
            int rr = mt*16 + (l & 15);
            int grow = (rr >> 3)*HID + p*8 + (rr & 7);
            const float* wrow = W_hh + grow*HID;
            #pragma unroll
            for (int kc = 0; kc < 16; ++kc) {
                int k0 = kc*32 + (l >> 4)*8;
                float4 f0 = *(const float4*)(wrow + k0);
                float4 f1 = *(const float4*)(wrow + k0 + 4);
                bf16x8 v;
                v[0]=(__bf16)f0.x; v[1]=(__bf16)f0.y; v[2]=(__bf16)f0.z; v[3]=(__bf16)f0.w;
                v[4]=(__bf16)f1.x; v[5]=(__bf16)f1.y; v[6]=(__bf16)f1.z; v[7]=(__bf16)f1.w;
                wfrag[mt][kc] = v;
            }
        }
        for (int x = tid; x < 8*64; x += 256) ((float*)c_lds)[x] = 0.0f;
        __syncthreads();

        int ulA = tid >> 6;     // 0..3 (thread also handles ulA+4)
        int bA  = tid & 63;

        for (int t = 0; t < TSTEPS; ++t) {
            // Xp gate-bias prefetch (precomputed; hides under MFMA phase)
            float xg[2][4];
            {
                const float* xpt = Xp + (size_t)t*GATES*64;
                int u0 = p*8 + ulA;
                #pragma unroll
                for (int g = 0; g < 4; ++g) {
                    xg[0][g] = xpt[((size_t)g*512 + u0    )*64 + bA];
                    xg[1][g] = xpt[((size_t)g*512 + u0 + 4)*64 + bA];
                }
            }

            if (t == 0) {
                for (int x = tid; x < 32*64; x += 256) ((float*)gates_lds)[x] = 0.0f;
            } else {
                int bb = w*16 + (l & 15);
                // K-chunk stride = 32 bf16 = 64 B = 8 u64 (stride-fixed, r3)
                const u64* hq = (const u64*)(h_all + (size_t)(t-1)*BATCH*HID + bb*HID + (l >> 4)*8);
                u64 hl[16][2];
                #pragma unroll
                for (int kc = 0; kc < 16; ++kc) {
                    hl[kc][0] = agent_load_u64(hq + kc*8);
                    hl[kc][1] = agent_load_u64(hq + kc*8 + 1);
                }
                f32x4 acc0 = {0.f,0.f,0.f,0.f};
                f32x4 acc1 = {0.f,0.f,0.f,0.f};
                #pragma unroll
                for (int kc = 0; kc < 16; ++kc) {
                    union { bf16x8 v; u64 u[2]; } uu;
                    uu.u[0] = hl[kc][0]; uu.u[1] = hl[kc][1];
                    acc0 = __builtin_amdgcn_mfma_f32_16x16x32_bf16(wfrag[0][kc], uu.v, acc0, 0, 0, 0);
                    acc1 = __builtin_amdgcn_mfma_f32_16x16x32_bf16(wfrag[1][kc], uu.v, acc1, 0, 0, 0);
                }
                #pragma unroll
                for (int j = 0; j < 4; ++j) {
                    gates_lds[(l>>4)*4 + j][bb]      = acc0[j];
                    gates_lds[16 + (l>>4)*4 + j][bb] = acc1[j];
                }
            }
            __syncthreads();

            // cell update: 8 units x 64 batches -> 2 items/thread
            #pragma unroll
            for (int half = 0; half < 2; ++half) {
                int ul = ulA + half*4;
                int b  = bA;
                float gi = gates_lds[ul][b]      + xg[half][0];
                float gf = gates_lds[8+ul][b]    + xg[half][1];
                float gg = gates_lds[16+ul][b]   + xg[half][2];
                float go = gates_lds[24+ul][b]   + xg[half][3];
                float ig = 1.0f/(1.0f + expf(-gi));
                float fg = 1.0f/(1.0f + expf(-gf));
                float gv = tanhf(gg);
                float og = 1.0f/(1.0f + expf(-go));
                float c = fg * c_lds[ul][b] + ig * gv;
                c_lds[ul][b] = c;
                float h = og * tanhf(c);
                h_s[b][ul] = (__bf16)h;
            }
            __syncthreads();   // h_s complete

            // coalesced sc1 store: 64 rows x 16B, one dword per thread
            {
                int row = tid >> 2, seg = tid & 3;
                unsigned int val = ((const unsigned int*)&h_s[0][0])[row*4 + seg];
                unsigned int* dst = (unsigned int*)(h_all + ((size_t)t*BATCH + row)*HID + p*8);
                agent_store_u32(dst + seg, val);
            }
            __syncthreads();   // drains vmcnt(0): h stores at coherence point

            unsigned int tgt = (unsigned int)(t + 1);
            if (tid == 0) agent_store_u32(bar + p*32, tgt);   // arrival
            if (t < TSTEPS - 1 || p == 0) {
                if (tid < 64) {
                    while (agent_load_u32(bar + tid*32) < tgt)
                        __builtin_amdgcn_s_sleep(1);
                    asm volatile("" ::: "memory");
                    // wave-converged here => all 64 flags >= tgt observed
                    if (p == 0 && tid == 0) agent_store_u32(step_done, tgt);
                }
                __syncthreads();
            }
        }
        __builtin_amdgcn_s_setprio(0);
        // fall through: join the pred worker pool
    }

    // ================= pred workers (dynamic tiles) =================
    {
        __bf16 (*As)[40] = (__bf16(*)[40])(lds_raw);           // 128x40 bf16 = 10240B
        __bf16 (*Bs)[40] = (__bf16(*)[40])(lds_raw + 10240);   // 128x40 bf16 = 10240B
        int wm = (w >> 1), wn = (w & 1);

        for (;;) {
            if (tid == 0)
                tile_sh = __hip_atomic_fetch_add(tile_cnt, 1u, __ATOMIC_RELAXED,
                                                 __HIP_MEMORY_SCOPE_AGENT);
            __syncthreads();
            unsigned int tile = tile_sh;
            __syncthreads();           // everyone read tile_sh before next overwrite
            if (tile >= TOT_TILES) break;
            int mtile = tile / NT_N;
            int ntile = tile % NT_N;
            int thi = (mtile*128 + 127) >> 6;
            if (thi > TSTEPS - 1) thi = TSTEPS - 1;
            unsigned int need = (unsigned int)(thi + 1);
            if (tid == 0) {
                while (agent_load_u32(step_done) < need)
                    __builtin_amdgcn_s_sleep(8);
            }
            __syncthreads();           // all As loads ordered after the poll
            asm volatile("" ::: "memory");

            f32x4 acc[4][4];
            #pragma unroll
            for (int i = 0; i < 4; ++i)
                #pragma unroll
                for (int j = 0; j < 4; ++j)
                    acc[i][j] = (f32x4){0.f,0.f,0.f,0.f};

            for (int kc = 0; kc < 16; ++kc) {
                __syncthreads();
                #pragma unroll
                for (int j = 0; j < 2; ++j) {
                    int idx = tid + j*256;      // 0..511
                    int row = idx >> 2, seg = idx & 3;
                    int rg = mtile*128 + row;
                    bf16x8 v;
                    if (rg < TSTEPS*BATCH) {
                        v = *(const bf16x8*)(h_all + (size_t)rg*HID + kc*32 + seg*8);
                    } else {
                        #pragma unroll
                        for (int q = 0; q < 8; ++q) v[q] = (__bf16)0.0f;
                    }
                    *(bf16x8*)&As[row][seg*8] = v;
                    int cg = ntile*128 + row;
                    *(bf16x8*)&Bs[row][seg*8] = *(const bf16x8*)(wdcb + (size_t)cg*HID + kc*32 + seg*8);
                }
                __syncthreads();
                bf16x8 af[4], bf[4];
                #pragma unroll
                for (int s = 0; s < 4; ++s) {
                    af[s] = *(const bf16x8*)&As[wm*64 + s*16 + (l & 15)][(l >> 4)*8];
                    bf[s] = *(const bf16x8*)&Bs[wn*64 + s*16 + (l & 15)][(l >> 4)*8];
                }
                #pragma unroll
                for (int sm = 0; sm < 4; ++sm)
                    #pragma unroll
                    for (int sn = 0; sn < 4; ++sn)
                        acc[sm][sn] = __builtin_amdgcn_mfma_f32_16x16x32_bf16(af[sm], bf[sn], acc[sm][sn], 0, 0, 0);
            }

            #pragma unroll
            for (int sm = 0; sm < 4; ++sm) {
                #pragma unroll
                for (int j = 0; j < 4; ++j) {
                    int R = mtile*128 + wm*64 + sm*16 + (l >> 4)*4 + j;
                    if (R >= TSTEPS*BATCH) continue;
                    int t = R >> 6, b = R & 63;
                    int dl = ws_declen[b];
                    #pragma unroll
                    for (int sn = 0; sn < 4; ++sn) {
                        int C = ntile*128 + wn*64 + sn*16 + (l & 15);
                        float v = (t < dl) ? (acc[sm][sn][j] + wdc_b[C]) : 0.0f;
                        out[((size_t)b*TSTEPS + t)*NVOCAB + C] = v;
                    }
                }
            }
            __syncthreads();   // tile done before next staging overwrites As/Bs
        }
    }
}

extern "C" void kernel_launch(void* const* d_in, const int* in_sizes, int n_in,
                              void* d_out, int out_size, void* d_ws, size_t ws_size,
                              hipStream_t stream) {
    const float* l_total = (const float*)d_in[0];
    const int*   enc     = (const int*)d_in[1];
    const int*   caplen  = (const int*)d_in[2];
    const float* emb     = (const float*)d_in[3];
    const float* W_ih    = (const float*)d_in[4];
    const float* W_hh    = (const float*)d_in[5];
    const float* b_ih    = (const float*)d_in[6];
    const float* b_hh    = (const float*)d_in[7];
    const float* wdc_W   = (const float*)d_in[8];
    const float* wdc_b   = (const float*)d_in[9];

    float* out = (float*)d_out;
    char* ws = (char*)d_ws;

    unsigned int* step_done = (unsigned int*)(ws + WS_STEPDONE);
    unsigned int* tile_cnt  = (unsigned int*)(ws + WS_TILECNT);
    unsigned int* bar       = (unsigned int*)(ws + WS_BAR);
    int* ws_sort        = (int*)(ws + WS_SORT);
    int* ws_declen      = (int*)(ws + WS_DECLEN);
    int* ws_caps        = (int*)(ws + WS_CAPS);
    float* lt           = (float*)(ws + WS_LT);
    float* cst          = (float*)(ws + WS_CONST);
    float* Xp           = (float*)(ws + WS_XP);
    __bf16* h_all       = (__bf16*)(ws + WS_HALL);
    __bf16* wdcb        = (__bf16*)(ws + WS_WDCB);

    float* out_caps   = out + PRED_ELEMS;
    float* out_declen = out_caps + BATCH*40;
    float* out_sort   = out_declen + BATCH;

    k0_setup<<<1, 256, 0, stream>>>(caplen, enc, out_caps, out_declen, out_sort,
                                    ws_sort, ws_declen, ws_caps,
                                    step_done, tile_cnt, bar);
    k1_lt<<<BATCH, 256, 0, stream>>>(l_total, ws_sort, lt);
    k2_const<<<dim3(32, 2), 256, 0, stream>>>(W_ih, lt, b_ih, b_hh, cst);
    k3_xp<<<dim3(32, TSTEPS), 256, 0, stream>>>(W_ih, emb, ws_caps, cst, Xp);
    k4_cvt<<<2048, 256, 0, stream>>>(wdc_W, wdcb);
    k5_fused<<<GRID_BLOCKS, 256, 0, stream>>>(W_hh, Xp, h_all, bar,
                                              step_done, tile_cnt,
                                              wdcb, wdc_b, ws_declen, out);
}

// Round 7
// 874.120 us; speedup vs baseline: 1.0896x; 1.0753x over previous
//
#include <hip/hip_runtime.h>
#include <hip/hip_bf16.h>
#include <math.h>

typedef float f32x4 __attribute__((ext_vector_type(4)));
typedef __bf16 bf16x8 __attribute__((ext_vector_type(8)));
typedef __bf16 bf16x4 __attribute__((ext_vector_type(4)));
typedef unsigned long long u64;

#define BATCH   64
#define TSTEPS  39
#define HID     512
#define GATES   2048
#define NVOCAB  32000
#define EMBD    300
#define FEAT    1024
#define XDIM    1324

#define PRED_ELEMS (BATCH*TSTEPS*NVOCAB)   // 79,872,000
#define MROWS (TSTEPS*BATCH)               // 2496

#define NT_M 20          // mtiles (rows 2560, M=2496 padded)
#define NT_N 250         // ntiles (32000/128)
#define TOT_TILES (NT_M*NT_N)
#define REC_BLOCKS 64
#define GRID_BLOCKS 512  // 2 blocks/CU: pred workers get TLP (r4 had 1/CU)

// ws offsets (bytes), all 16B aligned
#define WS_STEPDONE 0
#define WS_TILECNT  128
#define WS_SORT     256
#define WS_DECLEN   512
#define WS_CAPS     1024
#define WS_BAR      16384       // 64 arrival flags, 128B apart (8 KB)
#define WS_LT       65536
#define WS_CONST    327680
#define WS_XP       1048576     // [39][2048][64] f32
#define WS_HALL     22020096    // [39][64][512] bf16
#define WS_WDCB     25165824    // [32000][512] bf16

// Agent-scope (LLC-coherent, L1/L2-bypassing) relaxed helpers. No
// buffer_inv / buffer_wbl2 is emitted; ordering is built by hand from
// __syncthreads() vmcnt-drains + the flag/step_done protocol.
__device__ __forceinline__ u64 agent_load_u64(const u64* p) {
    return __hip_atomic_load(p, __ATOMIC_RELAXED, __HIP_MEMORY_SCOPE_AGENT);
}
__device__ __forceinline__ unsigned int agent_load_u32(const unsigned int* p) {
    return __hip_atomic_load(p, __ATOMIC_RELAXED, __HIP_MEMORY_SCOPE_AGENT);
}
__device__ __forceinline__ void agent_store_u32(unsigned int* p, unsigned int v) {
    __hip_atomic_store(p, v, __ATOMIC_RELAXED, __HIP_MEMORY_SCOPE_AGENT);
}

// ---------------- K0: sort + caps gather + tail outputs + sync-state zero ----------------
__global__ void k0_setup(const int* caplen, const int* enc,
                         float* out_caps, float* out_declen, float* out_sort,
                         int* ws_sort, int* ws_declen, int* ws_caps,
                         unsigned int* step_done, unsigned int* tile_cnt,
                         unsigned int* bar) {
    __shared__ int L[BATCH];
    __shared__ int sind[BATCH];
    int tid = threadIdx.x;
    if (tid == 0) { *step_done = 0u; *tile_cnt = 0u; }
    for (int x = tid; x < 64*32; x += blockDim.x) bar[x] = 0u;
    if (tid < BATCH) L[tid] = caplen[tid];
    __syncthreads();
    if (tid < BATCH) {
        int len = L[tid];
        int rank = 0;
        for (int j = 0; j < BATCH; ++j) {
            int lj = L[j];
            if (lj > len || (lj == len && j < tid)) rank++;
        }
        sind[rank] = tid;   // stable descending argsort(-lengths)
    }
    __syncthreads();
    if (tid < BATCH) {
        int src = sind[tid];
        ws_sort[tid] = src;
        int dl = L[src] - 1;
        ws_declen[tid] = dl;
        out_declen[tid] = (float)dl;
        out_sort[tid] = (float)src;
    }
    __syncthreads();
    for (int x = tid; x < BATCH*40; x += blockDim.x) {
        int b = x / 40, t = x % 40;
        int v = enc[sind[b]*40 + t];
        ws_caps[x] = v;
        out_caps[x] = (float)v;
    }
}

// ---------------- K1: lt[b][k] = sum_s l_total[s][sort[b]][k] ----------------
__global__ void k1_lt(const float* l_total, const int* ws_sort, float* lt) {
    int b = blockIdx.x;
    int ob = ws_sort[b];
    for (int k4 = threadIdx.x; k4 < FEAT/4; k4 += blockDim.x) {
        float4 a = ((const float4*)(l_total + (0*BATCH + ob)*FEAT))[k4];
        float4 c = ((const float4*)(l_total + (1*BATCH + ob)*FEAT))[k4];
        float4 d = ((const float4*)(l_total + (2*BATCH + ob)*FEAT))[k4];
        float4 r;
        r.x = a.x + c.x + d.x;  r.y = a.y + c.y + d.y;
        r.z = a.z + c.z + d.z;  r.w = a.w + c.w + d.w;
        ((float4*)(lt + b*FEAT))[k4] = r;
    }
}

// ---------------- K2: const[c][b] = bias[c] + sum_k lt[b][k]*W_ih[c][300+k] ----------------
__global__ void k2_const(const float* W_ih, const float* lt,
                         const float* b_ih, const float* b_hh, float* cst) {
    __shared__ float As[32][68];
    __shared__ float Bs[32][36];
    int ctile = blockIdx.x;   // 0..31
    int btile = blockIdx.y;   // 0..1
    int tid = threadIdx.x;
    int ty = tid >> 4, tx = tid & 15;
    float acc[4][2] = {};
    for (int kc = 0; kc < 32; ++kc) {
        __syncthreads();
        #pragma unroll
        for (int j = 0; j < 8; ++j) {
            int idx = tid + j*256;
            int c = idx >> 5, k = idx & 31;
            As[k][c] = W_ih[(ctile*64 + c)*XDIM + 300 + kc*32 + k];
        }
        #pragma unroll
        for (int j = 0; j < 4; ++j) {
            int idx = tid + j*256;
            int b = idx >> 5, k = idx & 31;
            Bs[k][b] = lt[(btile*32 + b)*FEAT + kc*32 + k];
        }
        __syncthreads();
        for (int k = 0; k < 32; ++k) {
            float4 av = *(const float4*)&As[k][ty*4];
            float2 bv = *(const float2*)&Bs[k][tx*2];
            acc[0][0] += av.x*bv.x; acc[0][1] += av.x*bv.y;
            acc[1][0] += av.y*bv.x; acc[1][1] += av.y*bv.y;
            acc[2][0] += av.z*bv.x; acc[2][1] += av.z*bv.y;
            acc[3][0] += av.w*bv.x; acc[3][1] += av.w*bv.y;
        }
    }
    #pragma unroll
    for (int i = 0; i < 4; ++i) {
        int cg = ctile*64 + ty*4 + i;
        float bias = b_ih[cg] + b_hh[cg];
        float2 o;
        o.x = acc[i][0] + bias; o.y = acc[i][1] + bias;
        *(float2*)&cst[cg*64 + btile*32 + tx*2] = o;
    }
}

// ---------------- K3: Xp[t][c][b] = const[c][b] + sum_{k<300} emb[tok[t,b]][k]*W_ih[c][k] ----------------
__global__ void k3_xp(const float* W_ih, const float* emb, const int* ws_caps,
                      const float* cst, float* Xp) {
    __shared__ float As[20][68];
    __shared__ float Bs[20][68];
    int ctile = blockIdx.x;   // 0..31
    int t = blockIdx.y;       // 0..38
    int tid = threadIdx.x;
    int ty = tid >> 4, tx = tid & 15;
    float acc[4][4] = {};
    for (int kc = 0; kc < 15; ++kc) {
        __syncthreads();
        #pragma unroll
        for (int j = 0; j < 5; ++j) {
            int idx = tid + j*256;   // 1280
            int c = idx / 20, k = idx % 20;
            As[k][c] = W_ih[(ctile*64 + c)*XDIM + kc*20 + k];
        }
        #pragma unroll
        for (int j = 0; j < 5; ++j) {
            int idx = tid + j*256;
            int b = idx / 20, k = idx % 20;
            int tok = ws_caps[b*40 + t];
            Bs[k][b] = emb[tok*EMBD + kc*20 + k];
        }
        __syncthreads();
        for (int k = 0; k < 20; ++k) {
            float4 av = *(const float4*)&As[k][ty*4];
            float4 bv = *(const float4*)&Bs[k][tx*4];
            acc[0][0] += av.x*bv.x; acc[0][1] += av.x*bv.y; acc[0][2] += av.x*bv.z; acc[0][3] += av.x*bv.w;
            acc[1][0] += av.y*bv.x; acc[1][1] += av.y*bv.y; acc[1][2] += av.y*bv.z; acc[1][3] += av.y*bv.w;
            acc[2][0] += av.z*bv.x; acc[2][1] += av.z*bv.y; acc[2][2] += av.z*bv.z; acc[2][3] += av.z*bv.w;
            acc[3][0] += av.w*bv.x; acc[3][1] += av.w*bv.y; acc[3][2] += av.w*bv.z; acc[3][3] += av.w*bv.w;
        }
    }
    #pragma unroll
    for (int i = 0; i < 4; ++i) {
        int cg = ctile*64 + ty*4 + i;
        float4 cs = *(const float4*)&cst[cg*64 + tx*4];
        float4 o;
        o.x = acc[i][0] + cs.x; o.y = acc[i][1] + cs.y;
        o.z = acc[i][2] + cs.z; o.w = acc[i][3] + cs.w;
        *(float4*)&Xp[(t*GATES + cg)*64 + tx*4] = o;
    }
}

// ---------------- K4: wdc_W fp32 -> bf16 ----------------
__global__ void k4_cvt(const float* wdc, __bf16* wdcb) {
    int n4 = NVOCAB*HID/4;
    for (int i = blockIdx.x*blockDim.x + threadIdx.x; i < n4; i += gridDim.x*blockDim.x) {
        float4 v = ((const float4*)wdc)[i];
        bf16x4 o;
        o[0] = (__bf16)v.x; o[1] = (__bf16)v.y; o[2] = (__bf16)v.z; o[3] = (__bf16)v.w;
        ((bf16x4*)wdcb)[i] = o;
    }
}

// ---------------- K5 (fused): LSTM recurrence + streaming pred GEMM ----------------
// Blocks 0..63: recurrence (block p owns hidden units [8p,8p+8), flag barrier
//   per step, p==0 publishes step_done = t+1 after observing all 64 flags).
// Blocks 64..511 (+ rec blocks once done): persistent pred workers, dynamic
//   tiles off tile_cnt, gated on step_done covering the tile's t-range.
// Residency: 512 blocks x 4 waves x ~21KB LDS, 160 VGPR -> 2 blocks/CU, all
//   co-resident; pred never blocks rec -> deadlock-free.
// Freshness: h_all is touched ONLY via sc1 (agent) ops by rec; pred's plain
//   loads first-touch each line after step_done covers it -> fresh from LLC.
__global__ void __launch_bounds__(256) k5_fused(const float* W_hh, const float* Xp,
                                                __bf16* h_all, unsigned int* bar,
                                                unsigned int* step_done, unsigned int* tile_cnt,
                                                const __bf16* wdcb, const float* wdc_b,
                                                const int* ws_declen, float* out) {
    __shared__ __align__(16) char lds_raw[20480];
    __shared__ unsigned int tile_sh;
    int tid = threadIdx.x;
    int l = tid & 63, w = tid >> 6;

    if (blockIdx.x < REC_BLOCKS) {
        // ================= recurrence =================
        float (*gates_lds)[64] = (float(*)[64])(lds_raw);              // 32x64 f32 = 8KB
        float (*c_lds)[64]     = (float(*)[64])(lds_raw + 8192);       // 8x64 f32  = 2KB
        __bf16 (*h_s)[8]       = (__bf16(*)[8])(lds_raw + 10240);      // 64x8 bf16 = 1KB
        int p = blockIdx.x;

        __builtin_amdgcn_s_setprio(1);   // rec is the serial critical path; win
                                         // issue arbitration vs co-resident pred

        // Preload W fragments: 2 row-tiles x 16 K-chunks
        bf16x8 wfrag[2][16];
        #pragma unroll
        for (int mt = 0; mt < 2; ++mt) {
            int rr = mt*16 + (l & 15);
            int grow = (rr >> 3)*HID + p*8 + (rr & 7);
            const float* wrow = W_hh + grow*HID;
            #pragma unroll
            for (int kc = 0; kc < 16; ++kc) {
                int k0 = kc*32 + (l >> 4)*8;
                float4 f0 = *(const float4*)(wrow + k0);
                float4 f1 = *(const float4*)(wrow + k0 + 4);
                bf16x8 v;
                v[0]=(__bf16)f0.x; v[1]=(__bf16)f0.y; v[2]=(__bf16)f0.z; v[3]=(__bf16)f0.w;
                v[4]=(__bf16)f1.x; v[5]=(__bf16)f1.y; v[6]=(__bf16)f1.z; v[7]=(__bf16)f1.w;
                wfrag[mt][kc] = v;
            }
        }
        for (int x = tid; x < 8*64; x += 256) ((float*)c_lds)[x] = 0.0f;
        __syncthreads();

        int ulA = tid >> 6;     // 0..3 (thread also handles ulA+4)
        int bA  = tid & 63;

        for (int t = 0; t < TSTEPS; ++t) {
            // Xp gate-bias prefetch (precomputed; hides under MFMA phase)
            float xg[2][4];
            {
                const float* xpt = Xp + (size_t)t*GATES*64;
                int u0 = p*8 + ulA;
                #pragma unroll
                for (int g = 0; g < 4; ++g) {
                    xg[0][g] = xpt[((size_t)g*512 + u0    )*64 + bA];
                    xg[1][g] = xpt[((size_t)g*512 + u0 + 4)*64 + bA];
                }
            }

            if (t == 0) {
                for (int x = tid; x < 32*64; x += 256) ((float*)gates_lds)[x] = 0.0f;
            } else {
                int bb = w*16 + (l & 15);
                // K-chunk stride = 32 bf16 = 64 B = 8 u64
                const u64* hq = (const u64*)(h_all + (size_t)(t-1)*BATCH*HID + bb*HID + (l >> 4)*8);
                u64 hl[16][2];
                #pragma unroll
                for (int kc = 0; kc < 16; ++kc) {
                    hl[kc][0] = agent_load_u64(hq + kc*8);
                    hl[kc][1] = agent_load_u64(hq + kc*8 + 1);
                }
                f32x4 acc0 = {0.f,0.f,0.f,0.f};
                f32x4 acc1 = {0.f,0.f,0.f,0.f};
                #pragma unroll
                for (int kc = 0; kc < 16; ++kc) {
                    union { bf16x8 v; u64 u[2]; } uu;
                    uu.u[0] = hl[kc][0]; uu.u[1] = hl[kc][1];
                    acc0 = __builtin_amdgcn_mfma_f32_16x16x32_bf16(wfrag[0][kc], uu.v, acc0, 0, 0, 0);
                    acc1 = __builtin_amdgcn_mfma_f32_16x16x32_bf16(wfrag[1][kc], uu.v, acc1, 0, 0, 0);
                }
                #pragma unroll
                for (int j = 0; j < 4; ++j) {
                    gates_lds[(l>>4)*4 + j][bb]      = acc0[j];
                    gates_lds[16 + (l>>4)*4 + j][bb] = acc1[j];
                }
            }
            __syncthreads();

            // cell update: 8 units x 64 batches -> 2 items/thread
            #pragma unroll
            for (int half = 0; half < 2; ++half) {
                int ul = ulA + half*4;
                int b  = bA;
                float gi = gates_lds[ul][b]      + xg[half][0];
                float gf = gates_lds[8+ul][b]    + xg[half][1];
                float gg = gates_lds[16+ul][b]   + xg[half][2];
                float go = gates_lds[24+ul][b]   + xg[half][3];
                float ig = 1.0f/(1.0f + expf(-gi));
                float fg = 1.0f/(1.0f + expf(-gf));
                float gv = tanhf(gg);
                float og = 1.0f/(1.0f + expf(-go));
                float c = fg * c_lds[ul][b] + ig * gv;
                c_lds[ul][b] = c;
                float h = og * tanhf(c);
                h_s[b][ul] = (__bf16)h;
            }
            __syncthreads();   // h_s complete

            // coalesced sc1 store: 64 rows x 16B, one dword per thread
            {
                int row = tid >> 2, seg = tid & 3;
                unsigned int val = ((const unsigned int*)&h_s[0][0])[row*4 + seg];
                unsigned int* dst = (unsigned int*)(h_all + ((size_t)t*BATCH + row)*HID + p*8);
                agent_store_u32(dst + seg, val);
            }
            __syncthreads();   // drains vmcnt(0): h stores at coherence point

            unsigned int tgt = (unsigned int)(t + 1);
            if (tid == 0) agent_store_u32(bar + p*32, tgt);   // arrival
            if (t < TSTEPS - 1 || p == 0) {
                if (tid < 64) {
                    while (agent_load_u32(bar + tid*32) < tgt)
                        __builtin_amdgcn_s_sleep(1);
                    asm volatile("" ::: "memory");
                    // wave-converged here => all 64 flags >= tgt observed
                    if (p == 0 && tid == 0) agent_store_u32(step_done, tgt);
                }
                __syncthreads();
            }
        }
        __builtin_amdgcn_s_setprio(0);
        // fall through: join the pred worker pool
    }

    // ================= pred workers (dynamic tiles) =================
    {
        __bf16 (*As)[40] = (__bf16(*)[40])(lds_raw);           // 128x40 bf16 = 10240B
        __bf16 (*Bs)[40] = (__bf16(*)[40])(lds_raw + 10240);   // 128x40 bf16 = 10240B
        int wm = (w >> 1), wn = (w & 1);

        for (;;) {
            if (tid == 0)
                tile_sh = __hip_atomic_fetch_add(tile_cnt, 1u, __ATOMIC_RELAXED,
                                                 __HIP_MEMORY_SCOPE_AGENT);
            __syncthreads();
            unsigned int tile = tile_sh;
            __syncthreads();           // everyone read tile_sh before next overwrite
            if (tile >= TOT_TILES) break;
            int mtile = tile / NT_N;
            int ntile = tile % NT_N;
            int thi = (mtile*128 + 127) >> 6;
            if (thi > TSTEPS - 1) thi = TSTEPS - 1;
            unsigned int need = (unsigned int)(thi + 1);
            if (tid == 0) {
                while (agent_load_u32(step_done) < need)
                    __builtin_amdgcn_s_sleep(8);
            }
            __syncthreads();           // all h loads ordered after the poll
            asm volatile("" ::: "memory");

            // register-prefetch pipeline: kc+1 loads issue under kc's MFMAs
            int seg = tid & 3, row0 = tid >> 2;      // rows row0, row0+64
            int rg0 = mtile*128 + row0;
            const __bf16* hb0 = h_all + (size_t)rg0*HID + seg*8;
            const __bf16* wb0 = wdcb + (size_t)(ntile*128 + row0)*HID + seg*8;

            bf16x8 zerov;
            #pragma unroll
            for (int q = 0; q < 8; ++q) zerov[q] = (__bf16)0.0f;

            bf16x8 a0, a1, b0, b1;
            auto LK = [&](int kc) {
                a0 = (rg0      < MROWS) ? *(const bf16x8*)(hb0 + kc*32)                  : zerov;
                a1 = (rg0 + 64 < MROWS) ? *(const bf16x8*)(hb0 + (size_t)64*HID + kc*32) : zerov;
                b0 = *(const bf16x8*)(wb0 + kc*32);
                b1 = *(const bf16x8*)(wb0 + (size_t)64*HID + kc*32);
            };
            LK(0);

            f32x4 acc[4][4];
            #pragma unroll
            for (int i = 0; i < 4; ++i)
                #pragma unroll
                for (int j = 0; j < 4; ++j)
                    acc[i][j] = (f32x4){0.f,0.f,0.f,0.f};

            for (int kc = 0; kc < 16; ++kc) {
                __syncthreads();                    // LDS free from prior compute
                *(bf16x8*)&As[row0][seg*8]      = a0;
                *(bf16x8*)&As[row0 + 64][seg*8] = a1;
                *(bf16x8*)&Bs[row0][seg*8]      = b0;
                *(bf16x8*)&Bs[row0 + 64][seg*8] = b1;
                __syncthreads();
                if (kc < 15) LK(kc + 1);            // next-kc loads fly under MFMA
                bf16x8 af[4], bf[4];
                #pragma unroll
                for (int s = 0; s < 4; ++s) {
                    af[s] = *(const bf16x8*)&As[wm*64 + s*16 + (l & 15)][(l >> 4)*8];
                    bf[s] = *(const bf16x8*)&Bs[wn*64 + s*16 + (l & 15)][(l >> 4)*8];
                }
                #pragma unroll
                for (int sm = 0; sm < 4; ++sm)
                    #pragma unroll
                    for (int sn = 0; sn < 4; ++sn)
                        acc[sm][sn] = __builtin_amdgcn_mfma_f32_16x16x32_bf16(af[sm], bf[sn], acc[sm][sn], 0, 0, 0);
            }

            #pragma unroll
            for (int sm = 0; sm < 4; ++sm) {
                #pragma unroll
                for (int j = 0; j < 4; ++j) {
                    int R = mtile*128 + wm*64 + sm*16 + (l >> 4)*4 + j;
                    if (R >= MROWS) continue;
                    int t = R >> 6, b = R & 63;
                    int dl = ws_declen[b];
                    #pragma unroll
                    for (int sn = 0; sn < 4; ++sn) {
                        int C = ntile*128 + wn*64 + sn*16 + (l & 15);
                        float v = (t < dl) ? (acc[sm][sn][j] + wdc_b[C]) : 0.0f;
                        out[((size_t)b*TSTEPS + t)*NVOCAB + C] = v;
                    }
                }
            }
            __syncthreads();   // all LDS reads done before next task restages
        }
    }
}

extern "C" void kernel_launch(void* const* d_in, const int* in_sizes, int n_in,
                              void* d_out, int out_size, void* d_ws, size_t ws_size,
                              hipStream_t stream) {
    const float* l_total = (const float*)d_in[0];
    const int*   enc     = (const int*)d_in[1];
    const int*   caplen  = (const int*)d_in[2];
    const float* emb     = (const float*)d_in[3];
    const float* W_ih    = (const float*)d_in[4];
    const float* W_hh    = (const float*)d_in[5];
    const float* b_ih    = (const float*)d_in[6];
    const float* b_hh    = (const float*)d_in[7];
    const float* wdc_W   = (const float*)d_in[8];
    const float* wdc_b   = (const float*)d_in[9];

    float* out = (float*)d_out;
    char* ws = (char*)d_ws;

    unsigned int* step_done = (unsigned int*)(ws + WS_STEPDONE);
    unsigned int* tile_cnt  = (unsigned int*)(ws + WS_TILECNT);
    unsigned int* bar       = (unsigned int*)(ws + WS_BAR);
    int* ws_sort        = (int*)(ws + WS_SORT);
    int* ws_declen      = (int*)(ws + WS_DECLEN);
    int* ws_caps        = (int*)(ws + WS_CAPS);
    float* lt           = (float*)(ws + WS_LT);
    float* cst          = (float*)(ws + WS_CONST);
    float* Xp           = (float*)(ws + WS_XP);
    __bf16* h_all       = (__bf16*)(ws + WS_HALL);
    __bf16* wdcb        = (__bf16*)(ws + WS_WDCB);

    float* out_caps   = out + PRED_ELEMS;
    float* out_declen = out_caps + BATCH*40;
    float* out_sort   = out_declen + BATCH;

    k0_setup<<<1, 256, 0, stream>>>(caplen, enc, out_caps, out_declen, out_sort,
                                    ws_sort, ws_declen, ws_caps,
                                    step_done, tile_cnt, bar);
    k1_lt<<<BATCH, 256, 0, stream>>>(l_total, ws_sort, lt);
    k2_const<<<dim3(32, 2), 256, 0, stream>>>(W_ih, lt, b_ih, b_hh, cst);
    k3_xp<<<dim3(32, TSTEPS), 256, 0, stream>>>(W_ih, emb, ws_caps, cst, Xp);
    k4_cvt<<<2048, 256, 0, stream>>>(wdc_W, wdcb);
    k5_fused<<<GRID_BLOCKS, 256, 0, stream>>>(W_hh, Xp, h_all, bar,
                                              step_done, tile_cnt,
                                              wdcb, wdc_b, ws_declen, out);
}